// Round 12
// baseline (68.719 us; speedup 1.0000x reference)
//
#include <hip/hip_runtime.h>
#include <cmath>

// Round 12: split prep + BARRIER-FREE wave-private streaming.
//
//   qprep (1 block, 256 thr): fixed-circuit 16x16 unitary -> A[81][4] in d_ws.
//   qmain (2048 blocks x 64 thr = 1 wave each): each wave owns a private
//     64-row x 68-word LDS tile (17.4 KB). Per tile: 16 coalesced 1KB loads
//     (register-prefetched one tile ahead), ds_write staging, lgkmcnt-only
//     ordering (ZERO s_barrier instructions in the whole kernel), per-lane
//     row GEMV vs s_load'ed W, transcendental tail, contraction vs s_load'ed
//     A (SMEM pipe). Waves free-run -> HBM queue kept full by TLP.
//
// Bank math (RS=68 words): read b128 quad = (lane+j) mod 8, write quad =
// (hi + chunk) mod 8 -- both uniform 8 lanes/quad = b128 floor, no padding
// hotspots. 8 waves/CU (LDS 17.4KB x 8 = 139KB).

// ---- prep kernel: verbatim round-10 (validated rounds 10-11) ----
__global__ __launch_bounds__(256) void qprep_kernel(
    const float* __restrict__ qw,   // [3][4][2]
    float* __restrict__ A_out)      // [81][4]
{
  __shared__ float sre[16][17];
  __shared__ float sim[16][17];
  __shared__ float M[4][16][16];
  const int tid = threadIdx.x;
  const int col = tid >> 4;
  const int u   = tid & 15;

  sre[col][u] = (u == col) ? 1.0f : 0.0f;
  sim[col][u] = 0.0f;
  __syncthreads();

#pragma unroll
  for (int l = 0; l < 3; ++l) {
#pragma unroll
    for (int w = 0; w < 4; ++w) {
      const int mask = 8 >> w;     // wire 0 = MSB
      float sh, ch, sh2, ch2;
      __sincosf(0.5f * qw[(l * 4 + w) * 2 + 0], &sh, &ch);    // RY
      __sincosf(0.5f * qw[(l * 4 + w) * 2 + 1], &sh2, &ch2);  // RZ
      const int ua = u & ~mask, ub = u | mask;
      const float ar = sre[col][ua], ai = sim[col][ua];
      const float br = sre[col][ub], bi = sim[col][ub];
      __syncthreads();
      float nr, ni;
      if (u & mask) { nr = sh * ar + ch * br; ni = sh * ai + ch * bi; }
      else          { nr = ch * ar - sh * br; ni = ch * ai - sh * bi; }
      float rr, ri;
      if (u & mask) { rr = ch2 * nr - sh2 * ni; ri = ch2 * ni + sh2 * nr; }
      else          { rr = ch2 * nr + sh2 * ni; ri = ch2 * ni - sh2 * nr; }
      sre[col][u] = rr; sim[col][u] = ri;
      __syncthreads();
    }
    int src = u;
    if (src & 1) src ^= 8;
    if (src & 2) src ^= 1;
    if (src & 4) src ^= 2;
    if (src & 8) src ^= 4;
    const float pr = sre[col][src], pi = sim[col][src];
    __syncthreads();
    sre[col][u] = pr; sim[col][u] = pi;
    __syncthreads();
  }

  for (int idx = tid; idx < 1024; idx += 256) {
    const int w = idx >> 8, s = (idx >> 4) & 15, t = idx & 15;
    const int mask = 8 >> w;
    float acc = 0.0f;
#pragma unroll
    for (int uu = 0; uu < 16; ++uu) {
      const float z = (uu & mask) ? -1.0f : 1.0f;
      acc += z * (sre[s][uu] * sre[t][uu] + sim[s][uu] * sim[t][uu]);
    }
    M[w][s][t] = acc;
  }
  __syncthreads();

  for (int idx = tid; idx < 324; idx += 256) {
    const int w = idx & 3, pq = idx >> 2;
    const int p = pq / 9, q = pq % 9;
    const int i0 = p / 3, i1 = p % 3, i2 = q / 3, i3 = q % 3;
    float acc = 0.0f;
#pragma unroll
    for (int comb = 0; comb < 16; ++comb) {
      int s = 0, t = 0;
      float coef = 0.0625f;
      int j;
      j = (comb >> 3) & 1; s |= j << 3; t |= ((i0 == 2) ? (j ^ 1) : j) << 3; if (i0 == 1 && j) coef = -coef;
      j = (comb >> 2) & 1; s |= j << 2; t |= ((i1 == 2) ? (j ^ 1) : j) << 2; if (i1 == 1 && j) coef = -coef;
      j = (comb >> 1) & 1; s |= j << 1; t |= ((i2 == 2) ? (j ^ 1) : j) << 1; if (i2 == 1 && j) coef = -coef;
      j = comb & 1;        s |= j;      t |= ((i3 == 2) ? (j ^ 1) : j);      if (i3 == 1 && j) coef = -coef;
      acc = fmaf(coef, M[w][s][t], acc);
    }
    A_out[idx] = acc;   // layout [pq*4 + w]
  }
}

// ---- main kernel: 1 wave per block, zero barriers ----
__global__ __launch_bounds__(64)
__attribute__((amdgpu_waves_per_eu(2, 2)))   // 256-VGPR budget: no spill
void qmain_kernel(
    const float* __restrict__ x,     // [B][64]
    const float* __restrict__ Wp,    // [4][64]
    const float* __restrict__ bp,    // [4]
    const float4* __restrict__ Aws,  // [81] float4 (d_ws)
    float* __restrict__ out)         // [B][4]
{
  constexpr int RS = 68;                         // row stride in words
  __shared__ alignas(16) float wlds[64 * RS];    // 17,408 B, wave-private

  const int lane = threadIdx.x;                  // 0..63
  const int hi   = lane >> 4;                    // row-in-quad for staging
  const int c4   = (lane & 15) << 2;             // owned chunk word offset
  const size_t wrow0 = (size_t)blockIdx.x * 256; // wave's 256 rows (4 tiles)

  const float4* xs  = reinterpret_cast<const float4*>(x);
  float4* out4      = reinterpret_cast<float4*>(out);

  // ---- prefetch tile 0 (16 x 1KB coalesced loads) ----
  float4 v[16];
  {
    const float4* src = xs + wrow0 * 16 + lane;
#pragma unroll
    for (int i = 0; i < 16; ++i) v[i] = src[i * 64];
  }

#pragma unroll
  for (int t = 0; t < 4; ++t) {
    const size_t r0 = wrow0 + (size_t)(t * 64);

    // stage tile t: lane's float4 i is row 4i+hi, chunk lane&15
#pragma unroll
    for (int i = 0; i < 16; ++i)
      *reinterpret_cast<float4*>(&wlds[(4 * i + hi) * RS + c4]) = v[i];

    // prefetch tile t+1: in flight under this tile's GEMV + tail
    if (t < 3) {
      const float4* src = xs + (r0 + 64) * 16 + lane;
#pragma unroll
      for (int i = 0; i < 16; ++i) v[i] = src[i * 64];
    }

    // wave-internal ordering: writes complete before reads (no s_barrier)
    asm volatile("s_waitcnt lgkmcnt(0)" ::: "memory");
    __builtin_amdgcn_sched_barrier(0);

    // GEMV on own row (16 x ds_read_b128, bank-balanced)
    float a0 = 0.f, a1 = 0.f, a2 = 0.f, a3 = 0.f;
#pragma unroll
    for (int j = 0; j < 16; ++j) {
      const float4 q =
          *reinterpret_cast<const float4*>(&wlds[lane * RS + j * 4]);
      a0 = fmaf(q.x, Wp[j * 4 + 0], a0);
      a0 = fmaf(q.y, Wp[j * 4 + 1], a0);
      a0 = fmaf(q.z, Wp[j * 4 + 2], a0);
      a0 = fmaf(q.w, Wp[j * 4 + 3], a0);
      a1 = fmaf(q.x, Wp[64 + j * 4 + 0], a1);
      a1 = fmaf(q.y, Wp[64 + j * 4 + 1], a1);
      a1 = fmaf(q.z, Wp[64 + j * 4 + 2], a1);
      a1 = fmaf(q.w, Wp[64 + j * 4 + 3], a1);
      a2 = fmaf(q.x, Wp[128 + j * 4 + 0], a2);
      a2 = fmaf(q.y, Wp[128 + j * 4 + 1], a2);
      a2 = fmaf(q.z, Wp[128 + j * 4 + 2], a2);
      a2 = fmaf(q.w, Wp[128 + j * 4 + 3], a2);
      a3 = fmaf(q.x, Wp[192 + j * 4 + 0], a3);
      a3 = fmaf(q.y, Wp[192 + j * 4 + 1], a3);
      a3 = fmaf(q.z, Wp[192 + j * 4 + 2], a3);
      a3 = fmaf(q.w, Wp[192 + j * 4 + 3], a3);
    }

    // tail: tanh (exp form), sincos, g/h, 81-term contraction vs s_load A
    const float t0 = 1.0f - 2.0f / (__expf(2.0f * (a0 + bp[0])) + 1.0f);
    const float t1 = 1.0f - 2.0f / (__expf(2.0f * (a1 + bp[1])) + 1.0f);
    const float t2 = 1.0f - 2.0f / (__expf(2.0f * (a2 + bp[2])) + 1.0f);
    const float t3 = 1.0f - 2.0f / (__expf(2.0f * (a3 + bp[3])) + 1.0f);

    float c0, s0, c1, s1, c2, s2, c3, s3;
    __sincosf(t0, &s0, &c0); __sincosf(t1, &s1, &c1);
    __sincosf(t2, &s2, &c2); __sincosf(t3, &s3, &c3);

    const float g[9] = {1.f, c1, s1, c0, c0 * c1, c0 * s1,
                        s0, s0 * c1, s0 * s1};
    const float h[9] = {1.f, c3, s3, c2, c2 * c3, c2 * s3,
                        s2, s2 * c3, s2 * s3};

    float e0 = 0.f, e1 = 0.f, e2 = 0.f, e3 = 0.f;
#pragma unroll
    for (int p = 0; p < 9; ++p) {
#pragma unroll
      for (int q2 = 0; q2 < 9; ++q2) {
        const float4 a4 = Aws[p * 9 + q2];   // uniform s_load, SMEM pipe
        const float tt = g[p] * h[q2];
        e0 = fmaf(a4.x, tt, e0); e1 = fmaf(a4.y, tt, e1);
        e2 = fmaf(a4.z, tt, e2); e3 = fmaf(a4.w, tt, e3);
      }
    }
    out4[r0 + lane] = make_float4(e0, e1, e2, e3);
  }
}

extern "C" void kernel_launch(void* const* d_in, const int* in_sizes, int n_in,
                              void* d_out, int out_size, void* d_ws, size_t ws_size,
                              hipStream_t stream) {
  const float* x  = (const float*)d_in[0];
  const float* Wp = (const float*)d_in[1];
  const float* bp = (const float*)d_in[2];
  const float* qw = (const float*)d_in[3];
  float* out = (float*)d_out;
  float* A = (float*)d_ws;   // 324 floats
  (void)n_in; (void)out_size; (void)ws_size;

  qprep_kernel<<<1, 256, 0, stream>>>(qw, A);

  const int B = in_sizes[0] / 64;   // 524288 rows
  qmain_kernel<<<B / 256, 64, 0, stream>>>(x, Wp, bp,
                                           (const float4*)A, out);
}

// Round 13
// 40.981 us; speedup vs baseline: 1.6768x; 1.6768x over previous
//
#include <hip/hip_runtime.h>
#include <cmath>

// Round 13: split prep + BARRIER-FREE MFMA main kernel.
//
//   qprep (1 block): fixed 3-layer circuit -> 16x16 unitary -> A[81][4] in
//     d_ws (round-10 verbatim, validated).
//   qmain (512 blocks x 256 thr = 4 waves, fully independent): per wave,
//     4 tiles of 64 rows. Per 16-row M-tile: A-fragment loaded DIRECTLY
//     from global (row = lane&15, k = (lane>>4)*8 + j), cvt to bf16,
//     2x mfma_f32_16x16x32_bf16 vs a resident W^T B-fragment -> all 64
//     dots in 2 instructions. C layout (col=lane&15, row=(lane>>4)*4+reg):
//     lanes col<4 write 4 floats to a wave-private 1KB LDS patch; each
//     lane reads back its row's 4 angles. DS ops are wave-internal and
//     in-order -> ZERO s_barrier / __syncthreads in the entire kernel.
//     Tail: tanh/sincos + 81-term contraction vs s_load'ed A (SMEM pipe).

typedef __attribute__((ext_vector_type(8))) short bf16x8;
typedef __attribute__((ext_vector_type(4))) float f32x4;

__device__ __forceinline__ short f2bf(float f) {
  const unsigned u = __float_as_uint(f);
  return (short)((u + 0x7FFF + ((u >> 16) & 1)) >> 16);   // RNE
}

// ---- prep kernel: verbatim round-10 (validated rounds 10-12) ----
__global__ __launch_bounds__(256) void qprep_kernel(
    const float* __restrict__ qw,   // [3][4][2]
    float* __restrict__ A_out)      // [81][4]
{
  __shared__ float sre[16][17];
  __shared__ float sim[16][17];
  __shared__ float M[4][16][16];
  const int tid = threadIdx.x;
  const int col = tid >> 4;
  const int u   = tid & 15;

  sre[col][u] = (u == col) ? 1.0f : 0.0f;
  sim[col][u] = 0.0f;
  __syncthreads();

#pragma unroll
  for (int l = 0; l < 3; ++l) {
#pragma unroll
    for (int w = 0; w < 4; ++w) {
      const int mask = 8 >> w;     // wire 0 = MSB
      float sh, ch, sh2, ch2;
      __sincosf(0.5f * qw[(l * 4 + w) * 2 + 0], &sh, &ch);    // RY
      __sincosf(0.5f * qw[(l * 4 + w) * 2 + 1], &sh2, &ch2);  // RZ
      const int ua = u & ~mask, ub = u | mask;
      const float ar = sre[col][ua], ai = sim[col][ua];
      const float br = sre[col][ub], bi = sim[col][ub];
      __syncthreads();
      float nr, ni;
      if (u & mask) { nr = sh * ar + ch * br; ni = sh * ai + ch * bi; }
      else          { nr = ch * ar - sh * br; ni = ch * ai - sh * bi; }
      float rr, ri;
      if (u & mask) { rr = ch2 * nr - sh2 * ni; ri = ch2 * ni + sh2 * nr; }
      else          { rr = ch2 * nr + sh2 * ni; ri = ch2 * ni - sh2 * nr; }
      sre[col][u] = rr; sim[col][u] = ri;
      __syncthreads();
    }
    int src = u;
    if (src & 1) src ^= 8;
    if (src & 2) src ^= 1;
    if (src & 4) src ^= 2;
    if (src & 8) src ^= 4;
    const float pr = sre[col][src], pi = sim[col][src];
    __syncthreads();
    sre[col][u] = pr; sim[col][u] = pi;
    __syncthreads();
  }

  for (int idx = tid; idx < 1024; idx += 256) {
    const int w = idx >> 8, s = (idx >> 4) & 15, t = idx & 15;
    const int mask = 8 >> w;
    float acc = 0.0f;
#pragma unroll
    for (int uu = 0; uu < 16; ++uu) {
      const float z = (uu & mask) ? -1.0f : 1.0f;
      acc += z * (sre[s][uu] * sre[t][uu] + sim[s][uu] * sim[t][uu]);
    }
    M[w][s][t] = acc;
  }
  __syncthreads();

  for (int idx = tid; idx < 324; idx += 256) {
    const int w = idx & 3, pq = idx >> 2;
    const int p = pq / 9, q = pq % 9;
    const int i0 = p / 3, i1 = p % 3, i2 = q / 3, i3 = q % 3;
    float acc = 0.0f;
#pragma unroll
    for (int comb = 0; comb < 16; ++comb) {
      int s = 0, t = 0;
      float coef = 0.0625f;
      int j;
      j = (comb >> 3) & 1; s |= j << 3; t |= ((i0 == 2) ? (j ^ 1) : j) << 3; if (i0 == 1 && j) coef = -coef;
      j = (comb >> 2) & 1; s |= j << 2; t |= ((i1 == 2) ? (j ^ 1) : j) << 2; if (i1 == 1 && j) coef = -coef;
      j = (comb >> 1) & 1; s |= j << 1; t |= ((i2 == 2) ? (j ^ 1) : j) << 1; if (i2 == 1 && j) coef = -coef;
      j = comb & 1;        s |= j;      t |= ((i3 == 2) ? (j ^ 1) : j);      if (i3 == 1 && j) coef = -coef;
      acc = fmaf(coef, M[w][s][t], acc);
    }
    A_out[idx] = acc;   // layout [pq*4 + w]
  }
}

// ---- main kernel: MFMA GEMV, zero barriers ----
__global__ __launch_bounds__(256)
__attribute__((amdgpu_waves_per_eu(4, 4)))   // 128-VGPR budget
void qmain_kernel(
    const float* __restrict__ x,     // [B][64]
    const float* __restrict__ Wp,    // [4][64]
    const float* __restrict__ bp,    // [4]
    const float4* __restrict__ Aws,  // [81] float4 (d_ws)
    float* __restrict__ out)         // [B][4]
{
  __shared__ float wlds[4][256];     // 1KB per wave: [row64][qubit4]

  const int tid  = threadIdx.x;
  const int lane = tid & 63;
  const int wid  = tid >> 6;
  const int arow = lane & 15;        // M-row within tile / C column
  const int kgrp = lane >> 4;        // k-group (k = kgrp*8 + j)
  float* myld = wlds[wid];

  const size_t wrow0 = ((size_t)blockIdx.x * 4 + wid) * 256;  // wave's rows

  // ---- B fragment: W^T, cols 0..3 real, 4..15 zero. Built once. ----
  // B[k][col]: col = lane&15, k = h*32 + kgrp*8 + j
  bf16x8 wf0, wf1;
#pragma unroll
  for (int j = 0; j < 8; ++j) {
    if (arow < 4) {
      wf0[j] = f2bf(Wp[arow * 64 + 0  + kgrp * 8 + j]);
      wf1[j] = f2bf(Wp[arow * 64 + 32 + kgrp * 8 + j]);
    } else {
      wf0[j] = 0; wf1[j] = 0;
    }
  }
  const f32x4 zero = {0.f, 0.f, 0.f, 0.f};

#pragma unroll
  for (int t = 0; t < 4; ++t) {
    const size_t r0 = wrow0 + (size_t)(t * 64);

    // ---- 4 M-tiles of 16 rows: global->bf16 frag->2 mfma->LDS patch ----
#pragma unroll
    for (int m = 0; m < 4; ++m) {
      const float* rp = x + (r0 + (size_t)(m * 16 + arow)) * 64 + kgrp * 8;
      const float4 u0 = *reinterpret_cast<const float4*>(rp);       // k-half0
      const float4 u1 = *reinterpret_cast<const float4*>(rp + 4);
      const float4 u2 = *reinterpret_cast<const float4*>(rp + 32);  // k-half1
      const float4 u3 = *reinterpret_cast<const float4*>(rp + 36);
      bf16x8 af0, af1;
      af0[0] = f2bf(u0.x); af0[1] = f2bf(u0.y); af0[2] = f2bf(u0.z);
      af0[3] = f2bf(u0.w); af0[4] = f2bf(u1.x); af0[5] = f2bf(u1.y);
      af0[6] = f2bf(u1.z); af0[7] = f2bf(u1.w);
      af1[0] = f2bf(u2.x); af1[1] = f2bf(u2.y); af1[2] = f2bf(u2.z);
      af1[3] = f2bf(u2.w); af1[4] = f2bf(u3.x); af1[5] = f2bf(u3.y);
      af1[6] = f2bf(u3.z); af1[7] = f2bf(u3.w);

      f32x4 acc = __builtin_amdgcn_mfma_f32_16x16x32_bf16(af0, wf0, zero, 0, 0, 0);
      acc = __builtin_amdgcn_mfma_f32_16x16x32_bf16(af1, wf1, acc, 0, 0, 0);

      // C: col = lane&15 (= qubit), row = kgrp*4 + reg
      if (arow < 4) {
#pragma unroll
        for (int r = 0; r < 4; ++r)
          myld[(m * 16 + kgrp * 4 + r) * 4 + arow] = acc[r];
      }
    }

    // wave-internal LDS write->read ordering (compiler fence; DS queue is
    // in-order per wave, no s_barrier needed; zero-instruction fence)
    asm volatile("" ::: "memory");

    // ---- tail: lane owns row r0+lane ----
    const float4 ang = *reinterpret_cast<const float4*>(&myld[lane * 4]);
    const float t0 = 1.0f - 2.0f / (__expf(2.0f * (ang.x + bp[0])) + 1.0f);
    const float t1 = 1.0f - 2.0f / (__expf(2.0f * (ang.y + bp[1])) + 1.0f);
    const float t2 = 1.0f - 2.0f / (__expf(2.0f * (ang.z + bp[2])) + 1.0f);
    const float t3 = 1.0f - 2.0f / (__expf(2.0f * (ang.w + bp[3])) + 1.0f);

    float c0, s0, c1, s1, c2, s2, c3, s3;
    __sincosf(t0, &s0, &c0); __sincosf(t1, &s1, &c1);
    __sincosf(t2, &s2, &c2); __sincosf(t3, &s3, &c3);

    const float g[9] = {1.f, c1, s1, c0, c0 * c1, c0 * s1,
                        s0, s0 * c1, s0 * s1};
    const float h[9] = {1.f, c3, s3, c2, c2 * c3, c2 * s3,
                        s2, s2 * c3, s2 * s3};

    float e0 = 0.f, e1 = 0.f, e2 = 0.f, e3 = 0.f;
#pragma unroll
    for (int p = 0; p < 9; ++p) {
#pragma unroll
      for (int q2 = 0; q2 < 9; ++q2) {
        const float4 a4 = Aws[p * 9 + q2];   // uniform s_load, SMEM pipe
        const float tt = g[p] * h[q2];
        e0 = fmaf(a4.x, tt, e0); e1 = fmaf(a4.y, tt, e1);
        e2 = fmaf(a4.z, tt, e2); e3 = fmaf(a4.w, tt, e3);
      }
    }
    reinterpret_cast<float4*>(out)[r0 + lane] = make_float4(e0, e1, e2, e3);

    // keep tile t's LDS patch live until reads done before t+1 overwrites
    asm volatile("" ::: "memory");
  }
}

extern "C" void kernel_launch(void* const* d_in, const int* in_sizes, int n_in,
                              void* d_out, int out_size, void* d_ws, size_t ws_size,
                              hipStream_t stream) {
  const float* x  = (const float*)d_in[0];
  const float* Wp = (const float*)d_in[1];
  const float* bp = (const float*)d_in[2];
  const float* qw = (const float*)d_in[3];
  float* out = (float*)d_out;
  float* A = (float*)d_ws;   // 324 floats
  (void)n_in; (void)out_size; (void)ws_size;

  qprep_kernel<<<1, 256, 0, stream>>>(qw, A);

  const int B = in_sizes[0] / 64;   // 524288 rows
  qmain_kernel<<<B / 1024, 256, 0, stream>>>(x, Wp, bp,
                                             (const float4*)A, out);
}

// Round 14
// 37.380 us; speedup vs baseline: 1.8384x; 1.0963x over previous
//
#include <hip/hip_runtime.h>
#include <cmath>

// Round 14: r13's barrier-free MFMA structure + full software pipelining.
//   - 1024 blocks x 256 thr (4 blocks/CU, 16 waves/CU); each wave: 2 tiles
//     of 64 rows, fully independent (zero s_barrier in qmain).
//   - Per 16-row m-subtile: A-frag direct from global (row=lane&15,
//     k=(lane>>4)*8+j), cvt bf16, 2x mfma_f32_16x16x32_bf16 vs resident
//     W^T frag; C (col=lane&15, row=(lane>>4)*4+reg) -> wave-private LDS
//     patch; lane reads back its row's 4 angles.
//   - Pipeline: named ping-pong buffers (uaX/ubX); subtile m+1's loads
//     issue before subtile m's MFMA; tile t+1's first subtile issues
//     before tile t's tail -> its HBM latency hides under ~1600cy of tail.
//   - Tail: tanh/sincos + 81-term contraction vs s_load'ed A (SMEM pipe).

typedef __attribute__((ext_vector_type(8))) short bf16x8;
typedef __attribute__((ext_vector_type(4))) float f32x4;

__device__ __forceinline__ short f2bf(float f) {
  const unsigned u = __float_as_uint(f);
  return (short)((u + 0x7FFF + ((u >> 16) & 1)) >> 16);   // RNE
}

// ---- prep kernel: verbatim round-10 (validated rounds 10-13) ----
__global__ __launch_bounds__(256) void qprep_kernel(
    const float* __restrict__ qw,   // [3][4][2]
    float* __restrict__ A_out)      // [81][4]
{
  __shared__ float sre[16][17];
  __shared__ float sim[16][17];
  __shared__ float M[4][16][16];
  const int tid = threadIdx.x;
  const int col = tid >> 4;
  const int u   = tid & 15;

  sre[col][u] = (u == col) ? 1.0f : 0.0f;
  sim[col][u] = 0.0f;
  __syncthreads();

#pragma unroll
  for (int l = 0; l < 3; ++l) {
#pragma unroll
    for (int w = 0; w < 4; ++w) {
      const int mask = 8 >> w;     // wire 0 = MSB
      float sh, ch, sh2, ch2;
      __sincosf(0.5f * qw[(l * 4 + w) * 2 + 0], &sh, &ch);    // RY
      __sincosf(0.5f * qw[(l * 4 + w) * 2 + 1], &sh2, &ch2);  // RZ
      const int ua = u & ~mask, ub = u | mask;
      const float ar = sre[col][ua], ai = sim[col][ua];
      const float br = sre[col][ub], bi = sim[col][ub];
      __syncthreads();
      float nr, ni;
      if (u & mask) { nr = sh * ar + ch * br; ni = sh * ai + ch * bi; }
      else          { nr = ch * ar - sh * br; ni = ch * ai - sh * bi; }
      float rr, ri;
      if (u & mask) { rr = ch2 * nr - sh2 * ni; ri = ch2 * ni + sh2 * nr; }
      else          { rr = ch2 * nr + sh2 * ni; ri = ch2 * ni - sh2 * nr; }
      sre[col][u] = rr; sim[col][u] = ri;
      __syncthreads();
    }
    int src = u;
    if (src & 1) src ^= 8;
    if (src & 2) src ^= 1;
    if (src & 4) src ^= 2;
    if (src & 8) src ^= 4;
    const float pr = sre[col][src], pi = sim[col][src];
    __syncthreads();
    sre[col][u] = pr; sim[col][u] = pi;
    __syncthreads();
  }

  for (int idx = tid; idx < 1024; idx += 256) {
    const int w = idx >> 8, s = (idx >> 4) & 15, t = idx & 15;
    const int mask = 8 >> w;
    float acc = 0.0f;
#pragma unroll
    for (int uu = 0; uu < 16; ++uu) {
      const float z = (uu & mask) ? -1.0f : 1.0f;
      acc += z * (sre[s][uu] * sre[t][uu] + sim[s][uu] * sim[t][uu]);
    }
    M[w][s][t] = acc;
  }
  __syncthreads();

  for (int idx = tid; idx < 324; idx += 256) {
    const int w = idx & 3, pq = idx >> 2;
    const int p = pq / 9, q = pq % 9;
    const int i0 = p / 3, i1 = p % 3, i2 = q / 3, i3 = q % 3;
    float acc = 0.0f;
#pragma unroll
    for (int comb = 0; comb < 16; ++comb) {
      int s = 0, t = 0;
      float coef = 0.0625f;
      int j;
      j = (comb >> 3) & 1; s |= j << 3; t |= ((i0 == 2) ? (j ^ 1) : j) << 3; if (i0 == 1 && j) coef = -coef;
      j = (comb >> 2) & 1; s |= j << 2; t |= ((i1 == 2) ? (j ^ 1) : j) << 2; if (i1 == 1 && j) coef = -coef;
      j = (comb >> 1) & 1; s |= j << 1; t |= ((i2 == 2) ? (j ^ 1) : j) << 1; if (i2 == 1 && j) coef = -coef;
      j = comb & 1;        s |= j;      t |= ((i3 == 2) ? (j ^ 1) : j);      if (i3 == 1 && j) coef = -coef;
      acc = fmaf(coef, M[w][s][t], acc);
    }
    A_out[idx] = acc;   // layout [pq*4 + w]
  }
}

// load m-subtile (tile base R0) into 4 named float4 regs
#define LDSUB(V0, V1, V2, V3, R0, M) {                                      \
  const float* rp_ = x + ((R0) + (size_t)((M) * 16 + arow)) * 64 + kgrp * 8;\
  V0 = *reinterpret_cast<const float4*>(rp_);                               \
  V1 = *reinterpret_cast<const float4*>(rp_ + 4);                          \
  V2 = *reinterpret_cast<const float4*>(rp_ + 32);                         \
  V3 = *reinterpret_cast<const float4*>(rp_ + 36); }

// convert + 2x MFMA + scatter into wave LDS patch (rows M*16..M*16+15)
#define DOMFMA(V0, V1, V2, V3, M) {                                         \
  bf16x8 af0_, af1_;                                                        \
  af0_[0] = f2bf(V0.x); af0_[1] = f2bf(V0.y); af0_[2] = f2bf(V0.z);         \
  af0_[3] = f2bf(V0.w); af0_[4] = f2bf(V1.x); af0_[5] = f2bf(V1.y);         \
  af0_[6] = f2bf(V1.z); af0_[7] = f2bf(V1.w);                               \
  af1_[0] = f2bf(V2.x); af1_[1] = f2bf(V2.y); af1_[2] = f2bf(V2.z);         \
  af1_[3] = f2bf(V2.w); af1_[4] = f2bf(V3.x); af1_[5] = f2bf(V3.y);         \
  af1_[6] = f2bf(V3.z); af1_[7] = f2bf(V3.w);                               \
  f32x4 acc_ = __builtin_amdgcn_mfma_f32_16x16x32_bf16(af0_, wf0, zero, 0, 0, 0); \
  acc_ = __builtin_amdgcn_mfma_f32_16x16x32_bf16(af1_, wf1, acc_, 0, 0, 0); \
  if (arow < 4) {                                                           \
    _Pragma("unroll")                                                       \
    for (int r_ = 0; r_ < 4; ++r_)                                          \
      myld[((M) * 16 + kgrp * 4 + r_) * 4 + arow] = acc_[r_];               \
  } }

// tail for one 64-row tile at base R0 (lane owns row R0+lane)
#define TAIL(R0) {                                                          \
  asm volatile("" ::: "memory");                                            \
  const float4 ang = *reinterpret_cast<const float4*>(&myld[lane * 4]);     \
  const float t0 = 1.0f - 2.0f / (__expf(2.0f * (ang.x + bp[0])) + 1.0f);   \
  const float t1 = 1.0f - 2.0f / (__expf(2.0f * (ang.y + bp[1])) + 1.0f);   \
  const float t2 = 1.0f - 2.0f / (__expf(2.0f * (ang.z + bp[2])) + 1.0f);   \
  const float t3 = 1.0f - 2.0f / (__expf(2.0f * (ang.w + bp[3])) + 1.0f);   \
  float c0, s0, c1, s1, c2, s2, c3, s3;                                     \
  __sincosf(t0, &s0, &c0); __sincosf(t1, &s1, &c1);                         \
  __sincosf(t2, &s2, &c2); __sincosf(t3, &s3, &c3);                         \
  const float g[9] = {1.f, c1, s1, c0, c0 * c1, c0 * s1,                    \
                      s0, s0 * c1, s0 * s1};                                \
  const float h[9] = {1.f, c3, s3, c2, c2 * c3, c2 * s3,                    \
                      s2, s2 * c3, s2 * s3};                                \
  float e0 = 0.f, e1 = 0.f, e2 = 0.f, e3 = 0.f;                             \
  _Pragma("unroll")                                                         \
  for (int p_ = 0; p_ < 9; ++p_) {                                          \
    _Pragma("unroll")                                                       \
    for (int q_ = 0; q_ < 9; ++q_) {                                        \
      const float4 a4 = Aws[p_ * 9 + q_];                                   \
      const float tt = g[p_] * h[q_];                                       \
      e0 = fmaf(a4.x, tt, e0); e1 = fmaf(a4.y, tt, e1);                     \
      e2 = fmaf(a4.z, tt, e2); e3 = fmaf(a4.w, tt, e3);                     \
    }                                                                       \
  }                                                                         \
  reinterpret_cast<float4*>(out)[(R0) + lane] =                             \
      make_float4(e0, e1, e2, e3);                                          \
  asm volatile("" ::: "memory"); }

__global__ __launch_bounds__(256)
__attribute__((amdgpu_waves_per_eu(4, 4)))   // 128-VGPR budget
void qmain_kernel(
    const float* __restrict__ x,     // [B][64]
    const float* __restrict__ Wp,    // [4][64]
    const float* __restrict__ bp,    // [4]
    const float4* __restrict__ Aws,  // [81] float4 (d_ws)
    float* __restrict__ out)         // [B][4]
{
  __shared__ float wlds[4][256];     // 1KB per wave: [row64][qubit4]

  const int tid  = threadIdx.x;
  const int lane = tid & 63;
  const int wid  = tid >> 6;
  const int arow = lane & 15;        // M-row within subtile / C column
  const int kgrp = lane >> 4;        // k-group
  float* myld = wlds[wid];

  const size_t wrow0 = ((size_t)blockIdx.x * 4 + wid) * 128;  // 2 tiles

  // ---- B fragment: W^T, cols 0..3 real, 4..15 zero ----
  bf16x8 wf0, wf1;
#pragma unroll
  for (int j = 0; j < 8; ++j) {
    if (arow < 4) {
      wf0[j] = f2bf(Wp[arow * 64 + 0  + kgrp * 8 + j]);
      wf1[j] = f2bf(Wp[arow * 64 + 32 + kgrp * 8 + j]);
    } else {
      wf0[j] = 0; wf1[j] = 0;
    }
  }
  const f32x4 zero = {0.f, 0.f, 0.f, 0.f};

  const size_t r0 = wrow0;            // tile 0
  const size_t r1 = wrow0 + 64;       // tile 1

  float4 ua0, ua1, ua2, ua3, ub0, ub1, ub2, ub3;   // named ping-pong

  // ---- tile 0, pipelined: load m+1 before MFMA m ----
  LDSUB(ua0, ua1, ua2, ua3, r0, 0);
  LDSUB(ub0, ub1, ub2, ub3, r0, 1);
  DOMFMA(ua0, ua1, ua2, ua3, 0); LDSUB(ua0, ua1, ua2, ua3, r0, 2);
  DOMFMA(ub0, ub1, ub2, ub3, 1); LDSUB(ub0, ub1, ub2, ub3, r0, 3);
  DOMFMA(ua0, ua1, ua2, ua3, 2); LDSUB(ua0, ua1, ua2, ua3, r1, 0);  // t1.m0!
  DOMFMA(ub0, ub1, ub2, ub3, 3);

  TAIL(r0);   // ~1600cy of VALU: t1.m0's loads land underneath

  // ---- tile 1 ----
  LDSUB(ub0, ub1, ub2, ub3, r1, 1);
  DOMFMA(ua0, ua1, ua2, ua3, 0); LDSUB(ua0, ua1, ua2, ua3, r1, 2);
  DOMFMA(ub0, ub1, ub2, ub3, 1); LDSUB(ub0, ub1, ub2, ub3, r1, 3);
  DOMFMA(ua0, ua1, ua2, ua3, 2);
  DOMFMA(ub0, ub1, ub2, ub3, 3);

  TAIL(r1);
}

extern "C" void kernel_launch(void* const* d_in, const int* in_sizes, int n_in,
                              void* d_out, int out_size, void* d_ws, size_t ws_size,
                              hipStream_t stream) {
  const float* x  = (const float*)d_in[0];
  const float* Wp = (const float*)d_in[1];
  const float* bp = (const float*)d_in[2];
  const float* qw = (const float*)d_in[3];
  float* out = (float*)d_out;
  float* A = (float*)d_ws;   // 324 floats
  (void)n_in; (void)out_size; (void)ws_size;

  qprep_kernel<<<1, 256, 0, stream>>>(qw, A);

  const int B = in_sizes[0] / 64;   // 524288 rows
  qmain_kernel<<<B / 512, 256, 0, stream>>>(x, Wp, bp,
                                            (const float4*)A, out);
}